// Round 10
// baseline (350.334 us; speedup 1.0000x reference)
//
#include <hip/hip_runtime.h>
#include <hip/hip_bf16.h>

// WaveNet on MI355X — round 10: layer kernel reworked to 16 waves/block
// (1024 thr) with 16-position chunks (per-wave path halved, 4 waves/SIMD)
// and lgkmcnt-only barriers (no vmcnt(0) drain of Z/hf/hb stores per layer).
// Prep, 8-phase skip GEMM, and end GEMM verbatim from round 9 (passing).
//
// Layouts (p = original position in [0,8192)):
//   hf0/hf1 : [b][p][c] f32   residual stream (double-buffered per group)
//   hb0/hb1 : [b][p][c] bf16  shadow of hf (MFMA B-operand / taps)
//   Z       : [b][p4][q] bf16, q = layer*32+o
//   skipb   : [b][p4][s] bf16 (relu applied)
//   wA      : [40][64 rows][64 k] bf16 (permuted rows: D-frag == B-frag trick)
//   wR      : [40][32 c][32 o] bf16
//   wskB    : [512 s][1280 q] bf16
//   ewB     : [256 cls][512 s] bf16

#define BATCH   8
#define SEQ     8192
#define RES_CH  32
#define DIL_CH  32
#define SKIP_CH 512
#define CLASSES 256
#define NLAYERS 40
#define OUTLEN  4096
#define PSTART  (SEQ - OUTLEN)      // 4096
#define QTOT    (NLAYERS * DIL_CH)  // 1280

typedef __attribute__((ext_vector_type(8))) short bf16x8;
typedef __attribute__((ext_vector_type(4))) short short4_t;
typedef __attribute__((ext_vector_type(4))) float f32x4;

// f32 -> bf16 (RNE) via hardware cvt
__device__ __forceinline__ short f2bf(float x) {
    __bf16 b = (__bf16)x;
    return __builtin_bit_cast(short, b);
}
__device__ __forceinline__ float bf2f(short s) {
    return __uint_as_float(((unsigned)(unsigned short)s) << 16);
}
__device__ __forceinline__ float zact(float f, float g) {
    float a = __expf(fminf(-2.0f * f, 80.0f));
    float b = __expf(fminf(-g, 80.0f));
    return (1.0f - a) * __builtin_amdgcn_rcpf((1.0f + a) * (1.0f + b));
}
// layer-tile byte-offset swizzle (rows of 64B)
__device__ __forceinline__ int tswz(int row, int cb) {
    return row * 64 + (cb ^ (((row & 3) << 4) | ((row & 4) << 3)));
}
// barrier that orders LDS only (no vmcnt(0) drain of global stores)
__device__ __forceinline__ void lgkm_barrier() {
    asm volatile("s_waitcnt lgkmcnt(0)\n\ts_barrier" ::: "memory");
}

#define GLOAD_LDS16(g, l)                                                    \
    __builtin_amdgcn_global_load_lds(                                        \
        (const __attribute__((address_space(1))) unsigned int*)(g),          \
        (__attribute__((address_space(3))) unsigned int*)(l), 16, 0, 0)

// ---------------- prep (verbatim R9) ----------------
__global__ __launch_bounds__(256) void k_prep(
    const float* __restrict__ x, const float* __restrict__ sw,
    const float* __restrict__ fw, const float* __restrict__ gw,
    const float* __restrict__ rw, const float* __restrict__ wsk,
    const float* __restrict__ ew,
    float* __restrict__ hf, short* __restrict__ hb,
    short* __restrict__ wA, short* __restrict__ wR,
    short* __restrict__ wskB, short* __restrict__ ewB)
{
    const int gt = blockIdx.x * 256 + threadIdx.x;
    const int gn = gridDim.x * 256;
    for (int idx = gt; idx < BATCH * SEQ; idx += gn) {
        float v = x[idx];
        float* hp = hf + (size_t)idx * RES_CH;
        short* bp = hb + (size_t)idx * RES_CH;
#pragma unroll
        for (int c = 0; c < RES_CH; ++c) {
            float t = v * sw[c];
            hp[c] = t;
            bp[c] = f2bf(t);
        }
    }
    for (int idx = gt; idx < NLAYERS * 64 * 64; idx += gn) {
        int k = idx & 63, rho = (idx >> 6) & 63, i = idx >> 12;
        int tap = k >> 5, c = k & 31;
        int fgsel = rho >> 5, rr = rho & 31;
        int fp = rr >> 4, gg = (rr >> 2) & 3, e = rr & 3;
        int o = gg * 8 + fp * 4 + e;
        float v = fgsel ? gw[((i * 32 + o) * 32 + c) * 2 + tap]
                        : fw[((i * 32 + o) * 32 + c) * 2 + tap];
        wA[idx] = f2bf(v);
    }
    for (int idx = gt; idx < NLAYERS * 1024; idx += gn)
        wR[idx] = f2bf(rw[idx]);
    for (int idx = gt; idx < SKIP_CH * QTOT; idx += gn) {
        int s = idx / QTOT, q = idx - s * QTOT;
        int i = q >> 5, o = q & 31;
        wskB[idx] = f2bf(wsk[((size_t)i * SKIP_CH + s) * 32 + o]);
    }
    for (int idx = gt; idx < CLASSES * SKIP_CH; idx += gn)
        ewB[idx] = f2bf(ew[idx]);
}

// ---------------- fused layer-group kernel (16 waves, 16-pos chunks) -------
template<bool OWNED>
__device__ __forceinline__ void chunk16(
    int cp0, bool bglob, bool last, int d, int tog,
    const short* __restrict__ hbb, const float* __restrict__ hfb,
    float* __restrict__ hfo, short* __restrict__ hbo,
    short* __restrict__ zbb, int liq,
    const char* trd, char* tw,
    const bf16x8 (&av)[4][2], const bf16x8 (&avr)[2],
    f32x4 (*carryc)[2],
    int r, int g14)
{
    const int p = cp0 + r;
    const bool pv = (unsigned)p < SEQ;
    int pl = p < 0 ? 0 : (p >= SEQ ? SEQ - 1 : p);
    int pm = pl - d; if (pm < 0) pm = 0;

    // B fragments: bv0 = tap(p-d), bv1 = tap(p)
    bf16x8 bv0, bv1;
    if (bglob) {
        bv0 = *(const bf16x8*)(hbb + pm * 32 + g14 * 8);
        bv1 = *(const bf16x8*)(hbb + pl * 32 + g14 * 8);
    } else {
        int tr = pl - tog;
        bv0 = *(const bf16x8*)(trd + tswz(tr - d, g14 * 16));
        bv1 = *(const bf16x8*)(trd + tswz(tr, g14 * 16));
    }

    const f32x4 zero4 = {0.f, 0.f, 0.f, 0.f};
    f32x4 acc[4];
#pragma unroll
    for (int fi = 0; fi < 4; ++fi) acc[fi] = zero4;
#pragma unroll
    for (int fi = 0; fi < 4; ++fi)
        acc[fi] = __builtin_amdgcn_mfma_f32_16x16x32_bf16(av[fi][0], bv0, acc[fi], 0, 0, 0);
#pragma unroll
    for (int fi = 0; fi < 4; ++fi)
        acc[fi] = __builtin_amdgcn_mfma_f32_16x16x32_bf16(av[fi][1], bv1, acc[fi], 0, 0, 0);

    // permuted wA: lane (r,g) reg (fp,e) holds output o = g*8+fp*4+e at p
    // -> zv8 is the res-GEMM B-fragment AND the 16B Z-store vector.
    bf16x8 zv8;
#pragma unroll
    for (int fp = 0; fp < 2; ++fp)
#pragma unroll
        for (int e = 0; e < 4; ++e)
            zv8[fp * 4 + e] = f2bf(zact(acc[fp][e], acc[fp + 2][e]));

    if constexpr (OWNED) {
        if (pv && pl >= PSTART)
            *(bf16x8*)(zbb + (size_t)(pl - PSTART) * QTOT + liq + g14 * 8) = zv8;
    }

    // res GEMM C-in
    f32x4 racc[2];
    if constexpr (OWNED) {
        if (bglob) {
#pragma unroll
            for (int fi = 0; fi < 2; ++fi)
                racc[fi] = *(const f32x4*)(hfb + pl * 32 + fi * 16 + g14 * 4);
        } else {
#pragma unroll
            for (int fi = 0; fi < 2; ++fi)
                racc[fi] = (*carryc)[fi];
        }
    } else {
#pragma unroll
        for (int fi = 0; fi < 2; ++fi) {
            short4_t hv;
            if (bglob)
                hv = *(const short4_t*)(hbb + pl * 32 + fi * 16 + g14 * 4);
            else
                hv = *(const short4_t*)(trd + tswz(pl - tog, fi * 32 + g14 * 8));
            f32x4 cv;
#pragma unroll
            for (int e = 0; e < 4; ++e) cv[e] = bf2f(hv[e]);
            racc[fi] = cv;
        }
    }

#pragma unroll
    for (int fi = 0; fi < 2; ++fi)
        racc[fi] = __builtin_amdgcn_mfma_f32_16x16x32_bf16(avr[fi], zv8, racc[fi], 0, 0, 0);

    if constexpr (OWNED) {
#pragma unroll
        for (int fi = 0; fi < 2; ++fi) (*carryc)[fi] = racc[fi];
    }

    if (!last) {
        if (pv) {
            int tr = pl - tog;
#pragma unroll
            for (int fi = 0; fi < 2; ++fi) {
                short4_t sv;
#pragma unroll
                for (int e = 0; e < 4; ++e) sv[e] = f2bf(racc[fi][e]);
                *(short4_t*)(tw + tswz(tr, fi * 32 + g14 * 8)) = sv;
            }
        }
    } else {
        if constexpr (OWNED) {
            if (pv) {
#pragma unroll
                for (int fi = 0; fi < 2; ++fi) {
                    *(f32x4*)(hfo + pl * 32 + fi * 16 + g14 * 4) = racc[fi];
                    short4_t sv;
#pragma unroll
                    for (int e = 0; e < 4; ++e) sv[e] = f2bf(racc[fi][e]);
                    *(short4_t*)(hbo + pl * 32 + fi * 16 + g14 * 4) = sv;
                }
            }
        }
    }
}

// 16 waves / 1024 threads, S=256: wave w owns the 16-pos chunk at
// seg0 + w*16 (register carry); halo chunks (16-pos) split 16 ways.
template<int LC, int S, int TH, int NTB>
__global__ __launch_bounds__(1024, 4) void k_fused16(
    const float* __restrict__ hfin, const short* __restrict__ hbin,
    float* __restrict__ hfout, short* __restrict__ hbout,
    const short* __restrict__ wAg, const short* __restrict__ wRg,
    short* __restrict__ Z, int li0, int pminIn, int hsum, int segbase)
{
    constexpr int TROWS = TH + S;
    __shared__ short tile[NTB][TROWS][32];

    const int lane = threadIdx.x & 63;
    const int w    = threadIdx.x >> 6;    // 0..15
    const int r = lane & 15, g14 = lane >> 4;
    const int b = blockIdx.y;
    const int seg0 = segbase + blockIdx.x * S;
    const int tog  = seg0 - TH;

    const float* hfb = hfin + (size_t)b * SEQ * RES_CH;
    const short* hbb = hbin + (size_t)b * SEQ * RES_CH;
    float* hfo = hfout + (size_t)b * SEQ * RES_CH;
    short* hbo = hbout + (size_t)b * SEQ * RES_CH;
    short* zbb = Z + (size_t)b * OUTLEN * QTOT;

    f32x4 carry[2];
    int Ht = hsum, pmt = pminIn;

#pragma unroll 1
    for (int t = 0; t < LC; ++t) {
        const int d = 1 << ((li0 + t) % 10);
        Ht -= d; pmt += d;
        const bool bglob = (t == 0);
        const bool last  = (t == LC - 1);
        const short* wAl = wAg + (li0 + t) * 4096;
        const short* wRl = wRg + (li0 + t) * 1024;
        const int liq = (li0 + t) * DIL_CH;
        char* tw = (char*)&tile[t & (NTB - 1)][0][0];
        const char* trd = (const char*)&tile[(t + NTB - 1) & (NTB - 1)][0][0];

        bf16x8 av[4][2];
#pragma unroll
        for (int fi = 0; fi < 4; ++fi)
#pragma unroll
            for (int kt = 0; kt < 2; ++kt)
                av[fi][kt] = *(const bf16x8*)(wAl + (fi * 16 + r) * 64 + kt * 32 + g14 * 8);
        bf16x8 avr[2];
#pragma unroll
        for (int fi = 0; fi < 2; ++fi)
            avr[fi] = *(const bf16x8*)(wRl + (fi * 16 + r) * 32 + g14 * 8);

        // owned chunk
        {
            const int cp0 = seg0 + w * 16;
            chunk16<true>(cp0, bglob, last, d, tog, hbb, hfb, hfo, hbo,
                          zbb, liq, trd, tw, av, avr, &carry, r, g14);
        }
        // halo chunks (left of seg0), 16-pos, split 16 ways
        int lo = seg0 - Ht; if (lo < pmt) lo = pmt;
        const int nh = (seg0 - lo + 15) >> 4;
#pragma unroll 1
        for (int hc = w; hc < nh; hc += 16) {
            const int cp0 = seg0 - (hc + 1) * 16;
            chunk16<false>(cp0, bglob, last, d, tog, hbb, hfb, hfo, hbo,
                           zbb, liq, trd, tw, av, avr, nullptr, r, g14);
        }
        lgkm_barrier();
    }
}

// ---------------- skip GEMM: 8-phase counted-vmcnt (verbatim R9) -----------
__global__ __launch_bounds__(512, 1) void k_skip_8ph(
    const short* __restrict__ Z, const short* __restrict__ wskB,
    short* __restrict__ skipb)
{
    __shared__ short lds[2][32768];   // [parity][A:16384 shorts | B:16384]

    const int bid = blockIdx.x;       // 256 blocks
    const int b   = bid & 7;          // one batch per XCD
    const int sb  = (bid >> 3) & 1;
    const int pb  = bid >> 4;         // 0..15
    const int s0  = sb * 256;
    const int p0  = pb * 256;

    const int tid  = threadIdx.x;
    const int lane = tid & 63;
    const int w    = tid >> 6;        // 0..7
    const int wm   = w >> 2;          // 0..1 (s half)
    const int wn   = w & 3;           // 0..3 (p quarter)
    const int r = lane & 15, g = lane >> 4;

    const short* Ag = wskB + (size_t)s0 * QTOT;
    const short* Bg = Z + ((size_t)b * OUTLEN + p0) * QTOT;

    const int srow = tid >> 3;        // 0..63 (row within 64-row chunk)
    const int sblk = tid & 7;         // 16B block within 128B row

#define STG(PI, ISA, HH, KT)                                                  \
    {                                                                         \
        _Pragma("unroll") for (int j = 0; j < 2; ++j) {                       \
            int grow = (HH) * 128 + j * 64 + srow;                            \
            const short* gp = ((ISA) ? Ag : Bg) + (size_t)grow * QTOT         \
                              + (KT) * 64 + ((sblk ^ (grow & 7)) * 8);        \
            short* lp = &lds[PI][((ISA) ? 0 : 16384) +                        \
                                 ((HH) * 128 + j * 64 + w * 8) * 64];         \
            GLOAD_LDS16(gp, lp);                                              \
        }                                                                     \
    }

#define DS_A(dst, bufi, fi_, kk_)                                             \
    { int row_ = wm * 128 + (fi_) * 16 + r;                                   \
      dst = *(const bf16x8*)&lds[bufi][row_ * 64 + ((((kk_) * 4 + g) ^ (row_ & 7)) * 8)]; }
#define DS_B(dst, bufi, fj_, kk_)                                             \
    { int row_ = wn * 64 + (fj_) * 16 + r;                                    \
      dst = *(const bf16x8*)&lds[bufi][16384 + row_ * 64 + ((((kk_) * 4 + g) ^ (row_ & 7)) * 8)]; }

#define FENCE asm volatile("" ::: "memory")
#define VM4   asm volatile("s_waitcnt vmcnt(4)" ::: "memory")

#define PHASE(BUF, FIB, READB, STAGECODE, VMW)                                \
    {                                                                         \
        if (READB) {                                                          \
            _Pragma("unroll") for (int fj = 0; fj < 4; ++fj)                  \
                _Pragma("unroll") for (int kk = 0; kk < 2; ++kk)              \
                    DS_B(bv[fj][kk], BUF, fj, kk);                            \
        }                                                                     \
        bf16x8 a0k0, a0k1, a1k0, a1k1;                                        \
        DS_A(a0k0, BUF, FIB, 0); DS_A(a0k1, BUF, FIB, 1);                     \
        DS_A(a1k0, BUF, (FIB) + 1, 0); DS_A(a1k1, BUF, (FIB) + 1, 1);         \
        STAGECODE;                                                            \
        VMW;                                                                  \
        FENCE; __builtin_amdgcn_s_barrier(); FENCE;                           \
        __builtin_amdgcn_s_setprio(1);                                        \
        _Pragma("unroll") for (int fj = 0; fj < 4; ++fj) {                    \
            acc[FIB][fj] = __builtin_amdgcn_mfma_f32_16x16x32_bf16(           \
                a0k0, bv[fj][0], acc[FIB][fj], 0, 0, 0);                      \
            acc[FIB][fj] = __builtin_amdgcn_mfma_f32_16x16x32_bf16(           \
                a0k1, bv[fj][1], acc[FIB][fj], 0, 0, 0);                      \
            acc[(FIB) + 1][fj] = __builtin_amdgcn_mfma_f32_16x16x32_bf16(     \
                a1k0, bv[fj][0], acc[(FIB) + 1][fj], 0, 0, 0);                \
            acc[(FIB) + 1][fj] = __builtin_amdgcn_mfma_f32_16x16x32_bf16(     \
                a1k1, bv[fj][1], acc[(FIB) + 1][fj], 0, 0, 0);                \
        }                                                                     \
        __builtin_amdgcn_s_setprio(0);                                        \
        FENCE; __builtin_amdgcn_s_barrier(); FENCE;                           \
    }

    f32x4 acc[8][4];
    const f32x4 zero4 = {0.f, 0.f, 0.f, 0.f};
#pragma unroll
    for (int fi = 0; fi < 8; ++fi)
#pragma unroll
        for (int fj = 0; fj < 4; ++fj) acc[fi][fj] = zero4;

    bf16x8 bv[4][2];

    STG(0, 1, 0, 0) STG(0, 1, 1, 0) STG(0, 0, 0, 0) STG(0, 0, 1, 0)
    STG(1, 0, 0, 1) STG(1, 0, 1, 1)
    VM4;
    FENCE; __builtin_amdgcn_s_barrier(); FENCE;

    const int NIT = QTOT / 128;       // 10 iterations (2 K-tiles each)
#pragma unroll 1
    for (int i = 0; i < NIT; ++i) {
        const int k1 = 2 * i + 1;
        const int k2 = 2 * i + 2, k3 = 2 * i + 3;
        const bool more = (i + 1 < NIT);
        PHASE(0, 0, 1, STG(1, 1, 0, k1), )                       // ph0
        PHASE(0, 2, 0, STG(1, 1, 1, k1), )                       // ph1
        PHASE(0, 4, 0, if (more) STG(0, 0, 0, k2), )             // ph2
        PHASE(0, 6, 0, if (more) STG(0, 0, 1, k2), VM4)          // ph3
        PHASE(1, 0, 1, if (more) STG(0, 1, 0, k2), )             // ph4
        PHASE(1, 2, 0, if (more) STG(0, 1, 1, k2), )             // ph5
        PHASE(1, 4, 0, if (more) STG(1, 0, 0, k3), )             // ph6
        PHASE(1, 6, 0, if (more) STG(1, 0, 1, k3), VM4)          // ph7
    }

    short* skb = skipb + (size_t)b * OUTLEN * SKIP_CH;
#pragma unroll
    for (int fj = 0; fj < 4; ++fj) {
        int p = p0 + wn * 64 + fj * 16 + r;
#pragma unroll
        for (int fi = 0; fi < 8; ++fi) {
            int s = s0 + wm * 128 + fi * 16 + g * 4;
            short4_t v;
#pragma unroll
            for (int e = 0; e < 4; ++e) v[e] = f2bf(fmaxf(acc[fi][fj][e], 0.f));
            *(short4_t*)(skb + (size_t)p * SKIP_CH + s) = v;
        }
    }
#undef PHASE
#undef STG
#undef DS_A
#undef DS_B
}

// ---------------- end GEMM (m97 structure, verbatim R9) ----------------
#define EK_STAGE(bf, kt)                                                      \
    {                                                                         \
        _Pragma("unroll") for (int j = 0; j < 2; ++j) {                       \
            const short* ga = Ab + (size_t)(rb + j * 16 + l4) * SKIP_CH       \
                                 + (kt) * 32 + csw * 8;                       \
            GLOAD_LDS16(ga, &At[bf][(rb + j * 16) * 32]);                     \
            const short* gb = Bb + (size_t)(rb + j * 16 + l4) * SKIP_CH       \
                                 + (kt) * 32 + csw * 8;                       \
            GLOAD_LDS16(gb, &Bt[bf][(rb + j * 16) * 32]);                     \
        }                                                                     \
    }

__global__ __launch_bounds__(256) void k_end_m97(
    const short* __restrict__ skipB, const short* __restrict__ ewB,
    const float* __restrict__ eb, float* __restrict__ out)
{
    __shared__ short At[2][128 * 32];
    __shared__ short Bt[2][128 * 32];

    const int bid = blockIdx.x;          // 512 blocks
    const int b    = bid & 7;
    const int rest = bid >> 3;
    const int cb   = rest & 1;
    const int pb   = rest >> 1;
    const int c0   = cb * 128;
    const int p0   = pb * 128;

    const int lane = threadIdx.x & 63;
    const int w    = threadIdx.x >> 6;
    const int r = lane & 15, g14 = lane >> 4;
    const int soff = (w >> 1) * 64;
    const int poff = (w & 1) * 64;

    const short* Ab = ewB + (size_t)c0 * SKIP_CH;
    const short* Bb = skipB + ((size_t)b * OUTLEN + p0) * SKIP_CH;

    const int rb = w * 32;
    const int l4 = lane >> 2;
    const int c4 = lane & 3;
    const int csw = c4 ^ ((l4 >> 1) & 3);
    const int rsw = (g14 ^ ((r >> 1) & 3)) * 8;

    f32x4 acc[4][4];
    const f32x4 zero4 = {0.f, 0.f, 0.f, 0.f};
#pragma unroll
    for (int fi = 0; fi < 4; ++fi)
#pragma unroll
        for (int fj = 0; fj < 4; ++fj) acc[fi][fj] = zero4;

    EK_STAGE(0, 0)
    __syncthreads();

    int cur = 0;
#pragma unroll 1
    for (int kt = 0; kt < SKIP_CH / 32; ++kt) {
        if (kt + 1 < SKIP_CH / 32) EK_STAGE(cur ^ 1, kt + 1)

        bf16x8 av[4], bv[4];
#pragma unroll
        for (int fi = 0; fi < 4; ++fi)
            av[fi] = *(const bf16x8*)&At[cur][(soff + fi * 16 + r) * 32 + rsw];
#pragma unroll
        for (int fj = 0; fj < 4; ++fj)
            bv[fj] = *(const bf16x8*)&Bt[cur][(poff + fj * 16 + r) * 32 + rsw];

#pragma unroll
        for (int fi = 0; fi < 4; ++fi)
#pragma unroll
            for (int fj = 0; fj < 4; ++fj)
                acc[fi][fj] = __builtin_amdgcn_mfma_f32_16x16x32_bf16(
                    av[fi], bv[fj], acc[fi][fj], 0, 0, 0);

        __syncthreads();
        cur ^= 1;
    }

#pragma unroll
    for (int fj = 0; fj < 4; ++fj) {
        int p = p0 + poff + fj * 16 + r;
#pragma unroll
        for (int fi = 0; fi < 4; ++fi) {
            int cls = c0 + soff + fi * 16 + g14 * 4;
            f32x4 bias = *(const f32x4*)(eb + cls);
            f32x4 v;
#pragma unroll
            for (int e = 0; e < 4; ++e) v[e] = acc[fi][fj][e] + bias[e];
            *(f32x4*)(out + ((size_t)b * OUTLEN + p) * CLASSES + cls) = v;
        }
    }
}

extern "C" void kernel_launch(void* const* d_in, const int* in_sizes, int n_in,
                              void* d_out, int out_size, void* d_ws, size_t ws_size,
                              hipStream_t stream) {
    const float* x   = (const float*)d_in[0];
    const float* sw  = (const float*)d_in[1];
    const float* fw  = (const float*)d_in[2];
    const float* gw  = (const float*)d_in[3];
    const float* rw  = (const float*)d_in[4];
    const float* wsk = (const float*)d_in[5];
    const float* ew  = (const float*)d_in[6];
    const float* eb  = (const float*)d_in[7];
    float* out = (float*)d_out;

    const size_t HN = (size_t)BATCH * SEQ * RES_CH;
    float* hf0 = (float*)d_ws;
    float* hf1 = hf0 + HN;
    short* hb0 = (short*)(hf1 + HN);
    short* hb1 = hb0 + HN;
    short* Z     = hb1 + HN;
    short* skipb = Z + (size_t)BATCH * OUTLEN * QTOT;
    short* wA    = skipb + (size_t)BATCH * OUTLEN * SKIP_CH;
    short* wR    = wA + NLAYERS * 64 * 64;
    short* wskB  = wR + NLAYERS * 32 * 32;
    short* ewB   = wskB + (size_t)SKIP_CH * QTOT;

    k_prep<<<dim3(1024), 256, 0, stream>>>(x, sw, fw, gw, rw, wsk, ew,
                                           hf0, hb0, wA, wR, wskB, ewB);

    float* hf[2] = {hf0, hf1};
    short* hb[2] = {hb0, hb1};
    int cur = 0, pmin = 0;
    for (int dec = 0; dec < 4; ++dec) {
        int li0 = dec * 10;
        // group 1: d = 1..128 (8 layers), halo sum 255, S=256
        int segbase = pmin + 255;
        int nseg = (SEQ - segbase + 255) / 256;
        k_fused16<8, 256, 288, 2><<<dim3(nseg, BATCH), 1024, 0, stream>>>(
            hf[cur], hb[cur], hf[cur ^ 1], hb[cur ^ 1], wA, wR, Z,
            li0, pmin, 255, segbase);
        cur ^= 1; pmin = segbase;
        // group 2: d = 256, 512 (2 layers), halo sum 768, S=256
        segbase = pmin + 768;
        nseg = (SEQ - segbase + 255) / 256;
        k_fused16<2, 256, 512, 1><<<dim3(nseg, BATCH), 1024, 0, stream>>>(
            hf[cur], hb[cur], hf[cur ^ 1], hb[cur ^ 1], wA, wR, Z,
            li0 + 8, pmin, 768, segbase);
        cur ^= 1; pmin = segbase;
    }

    k_skip_8ph<<<dim3(256), 512, 0, stream>>>(Z, wskB, skipb);
    k_end_m97<<<dim3(512), 256, 0, stream>>>(skipb, ewB, eb, out);
}

// Round 11
// 304.782 us; speedup vs baseline: 1.1495x; 1.1495x over previous
//
#include <hip/hip_runtime.h>
#include <hip/hip_bf16.h>

// WaveNet on MI355X — round 11: exact round-9 structure (best: 304us) with
// ONE change: k_fused8's per-layer __syncthreads (which drains vmcnt(0),
// serializing scattered Z/h global stores every layer) is replaced by an
// lgkmcnt-only barrier (LDS tile ordering only; global stores drain in
// background — they are never read within the launch).
//
// Layouts (p = original position in [0,8192)):
//   hf0/hf1 : [b][p][c] f32   residual stream (double-buffered per group)
//   hb0/hb1 : [b][p][c] bf16  shadow of hf (MFMA B-operand / taps)
//   Z       : [b][p4][q] bf16, q = layer*32+o
//   skipb   : [b][p4][s] bf16 (relu applied)
//   wA      : [40][64 rows][64 k] bf16 (permuted rows: D-frag == B-frag trick)
//   wR      : [40][32 c][32 o] bf16
//   wskB    : [512 s][1280 q] bf16
//   ewB     : [256 cls][512 s] bf16

#define BATCH   8
#define SEQ     8192
#define RES_CH  32
#define DIL_CH  32
#define SKIP_CH 512
#define CLASSES 256
#define NLAYERS 40
#define OUTLEN  4096
#define PSTART  (SEQ - OUTLEN)      // 4096
#define QTOT    (NLAYERS * DIL_CH)  // 1280

typedef __attribute__((ext_vector_type(8))) short bf16x8;
typedef __attribute__((ext_vector_type(4))) short short4_t;
typedef __attribute__((ext_vector_type(4))) float f32x4;

// f32 -> bf16 (RNE) via hardware cvt
__device__ __forceinline__ short f2bf(float x) {
    __bf16 b = (__bf16)x;
    return __builtin_bit_cast(short, b);
}
__device__ __forceinline__ float bf2f(short s) {
    return __uint_as_float(((unsigned)(unsigned short)s) << 16);
}
__device__ __forceinline__ float zact(float f, float g) {
    float a = __expf(fminf(-2.0f * f, 80.0f));
    float b = __expf(fminf(-g, 80.0f));
    return (1.0f - a) * __builtin_amdgcn_rcpf((1.0f + a) * (1.0f + b));
}
// layer-tile byte-offset swizzle (rows of 64B)
__device__ __forceinline__ int tswz(int row, int cb) {
    return row * 64 + (cb ^ (((row & 3) << 4) | ((row & 4) << 3)));
}
// barrier ordering LDS only: no vmcnt(0) drain of global stores
__device__ __forceinline__ void lgkm_barrier() {
    asm volatile("s_waitcnt lgkmcnt(0)\n\ts_barrier" ::: "memory");
}

#define GLOAD_LDS16(g, l)                                                    \
    __builtin_amdgcn_global_load_lds(                                        \
        (const __attribute__((address_space(1))) unsigned int*)(g),          \
        (__attribute__((address_space(3))) unsigned int*)(l), 16, 0, 0)

// ---------------- prep (verbatim R9) ----------------
__global__ __launch_bounds__(256) void k_prep(
    const float* __restrict__ x, const float* __restrict__ sw,
    const float* __restrict__ fw, const float* __restrict__ gw,
    const float* __restrict__ rw, const float* __restrict__ wsk,
    const float* __restrict__ ew,
    float* __restrict__ hf, short* __restrict__ hb,
    short* __restrict__ wA, short* __restrict__ wR,
    short* __restrict__ wskB, short* __restrict__ ewB)
{
    const int gt = blockIdx.x * 256 + threadIdx.x;
    const int gn = gridDim.x * 256;
    for (int idx = gt; idx < BATCH * SEQ; idx += gn) {
        float v = x[idx];
        float* hp = hf + (size_t)idx * RES_CH;
        short* bp = hb + (size_t)idx * RES_CH;
#pragma unroll
        for (int c = 0; c < RES_CH; ++c) {
            float t = v * sw[c];
            hp[c] = t;
            bp[c] = f2bf(t);
        }
    }
    for (int idx = gt; idx < NLAYERS * 64 * 64; idx += gn) {
        int k = idx & 63, rho = (idx >> 6) & 63, i = idx >> 12;
        int tap = k >> 5, c = k & 31;
        int fgsel = rho >> 5, rr = rho & 31;
        int fp = rr >> 4, gg = (rr >> 2) & 3, e = rr & 3;
        int o = gg * 8 + fp * 4 + e;
        float v = fgsel ? gw[((i * 32 + o) * 32 + c) * 2 + tap]
                        : fw[((i * 32 + o) * 32 + c) * 2 + tap];
        wA[idx] = f2bf(v);
    }
    for (int idx = gt; idx < NLAYERS * 1024; idx += gn)
        wR[idx] = f2bf(rw[idx]);
    for (int idx = gt; idx < SKIP_CH * QTOT; idx += gn) {
        int s = idx / QTOT, q = idx - s * QTOT;
        int i = q >> 5, o = q & 31;
        wskB[idx] = f2bf(wsk[((size_t)i * SKIP_CH + s) * 32 + o]);
    }
    for (int idx = gt; idx < CLASSES * SKIP_CH; idx += gn)
        ewB[idx] = f2bf(ew[idx]);
}

// ---------------- fused layer-group kernel (verbatim R9 + lgkm barrier) ----
template<bool OWNED>
__device__ __forceinline__ void chunk_body(
    int cp0, bool bglob, bool last, int d, int tog,
    const short* __restrict__ hbb, const float* __restrict__ hfb,
    float* __restrict__ hfo, short* __restrict__ hbo,
    short* __restrict__ zbb, int liq,
    const char* trd, char* tw,
    const bf16x8 (&av)[4][2], const bf16x8 (&avr)[2],
    f32x4 (*carryc)[2][2],
    int r, int g14)
{
    int pl[2]; bool pv[2];
#pragma unroll
    for (int fj = 0; fj < 2; ++fj) {
        int p = cp0 + fj * 16 + r;
        pv[fj] = p < SEQ;
        pl[fj] = pv[fj] ? p : SEQ - 1;
    }

    bf16x8 bv[2][2];
    if (bglob) {
#pragma unroll
        for (int fj = 0; fj < 2; ++fj) {
            bv[fj][0] = *(const bf16x8*)(hbb + (pl[fj] - d) * 32 + g14 * 8);
            bv[fj][1] = *(const bf16x8*)(hbb + pl[fj] * 32 + g14 * 8);
        }
    } else {
#pragma unroll
        for (int fj = 0; fj < 2; ++fj) {
            int tr = pl[fj] - tog;
            bv[fj][0] = *(const bf16x8*)(trd + tswz(tr - d, g14 * 16));
            bv[fj][1] = *(const bf16x8*)(trd + tswz(tr, g14 * 16));
        }
    }

    const f32x4 zero4 = {0.f, 0.f, 0.f, 0.f};
    f32x4 acc[4][2];
#pragma unroll
    for (int fi = 0; fi < 4; ++fi)
#pragma unroll
        for (int fj = 0; fj < 2; ++fj) acc[fi][fj] = zero4;
#pragma unroll
    for (int kt = 0; kt < 2; ++kt)
#pragma unroll
        for (int fi = 0; fi < 4; ++fi)
#pragma unroll
            for (int fj = 0; fj < 2; ++fj)
                acc[fi][fj] = __builtin_amdgcn_mfma_f32_16x16x32_bf16(
                    av[fi][kt], bv[fj][kt], acc[fi][fj], 0, 0, 0);

    bf16x8 zv8[2];
#pragma unroll
    for (int fj = 0; fj < 2; ++fj)
#pragma unroll
        for (int fp = 0; fp < 2; ++fp)
#pragma unroll
            for (int e = 0; e < 4; ++e)
                zv8[fj][fp * 4 + e] =
                    f2bf(zact(acc[fp][fj][e], acc[fp + 2][fj][e]));

    if constexpr (OWNED) {
#pragma unroll
        for (int fj = 0; fj < 2; ++fj)
            if (pv[fj] && pl[fj] >= PSTART) {
                short* zp = zbb + (size_t)(pl[fj] - PSTART) * QTOT + liq;
                *(bf16x8*)(zp + g14 * 8) = zv8[fj];
            }
    }

    f32x4 racc[2][2];
    if constexpr (OWNED) {
        if (bglob) {
#pragma unroll
            for (int fi = 0; fi < 2; ++fi)
#pragma unroll
                for (int fj = 0; fj < 2; ++fj)
                    racc[fi][fj] = *(const f32x4*)(hfb + pl[fj] * 32 + fi * 16 + g14 * 4);
        } else {
#pragma unroll
            for (int fi = 0; fi < 2; ++fi)
#pragma unroll
                for (int fj = 0; fj < 2; ++fj)
                    racc[fi][fj] = (*carryc)[fi][fj];
        }
    } else {
#pragma unroll
        for (int fj = 0; fj < 2; ++fj)
#pragma unroll
            for (int fi = 0; fi < 2; ++fi) {
                short4_t hv;
                if (bglob)
                    hv = *(const short4_t*)(hbb + pl[fj] * 32 + fi * 16 + g14 * 4);
                else
                    hv = *(const short4_t*)(trd + tswz(pl[fj] - tog, fi * 32 + g14 * 8));
                f32x4 cv;
#pragma unroll
                for (int e = 0; e < 4; ++e) cv[e] = bf2f(hv[e]);
                racc[fi][fj] = cv;
            }
    }

#pragma unroll
    for (int fi = 0; fi < 2; ++fi)
#pragma unroll
        for (int fj = 0; fj < 2; ++fj)
            racc[fi][fj] = __builtin_amdgcn_mfma_f32_16x16x32_bf16(
                avr[fi], zv8[fj], racc[fi][fj], 0, 0, 0);

    if constexpr (OWNED) {
#pragma unroll
        for (int fi = 0; fi < 2; ++fi)
#pragma unroll
            for (int fj = 0; fj < 2; ++fj)
                (*carryc)[fi][fj] = racc[fi][fj];
    }

    if (!last) {
#pragma unroll
        for (int fj = 0; fj < 2; ++fj)
            if (pv[fj]) {
                int tr = pl[fj] - tog;
#pragma unroll
                for (int fi = 0; fi < 2; ++fi) {
                    short4_t sv;
#pragma unroll
                    for (int e = 0; e < 4; ++e) sv[e] = f2bf(racc[fi][fj][e]);
                    *(short4_t*)(tw + tswz(tr, fi * 32 + g14 * 8)) = sv;
                }
            }
    } else {
        if constexpr (OWNED) {
#pragma unroll
            for (int fj = 0; fj < 2; ++fj)
                if (pv[fj]) {
#pragma unroll
                    for (int fi = 0; fi < 2; ++fi) {
                        *(f32x4*)(hfo + pl[fj] * 32 + fi * 16 + g14 * 4) = racc[fi][fj];
                        short4_t sv;
#pragma unroll
                        for (int e = 0; e < 4; ++e) sv[e] = f2bf(racc[fi][fj][e]);
                        *(short4_t*)(hbo + pl[fj] * 32 + fi * 16 + g14 * 4) = sv;
                    }
                }
        }
    }
}

template<int LC, int S, int TH, int NTB>
__global__ __launch_bounds__(512, 2) void k_fused8(
    const float* __restrict__ hfin, const short* __restrict__ hbin,
    float* __restrict__ hfout, short* __restrict__ hbout,
    const short* __restrict__ wAg, const short* __restrict__ wRg,
    short* __restrict__ Z, int li0, int pminIn, int hsum, int segbase)
{
    constexpr int TROWS = TH + S;
    __shared__ short tile[NTB][TROWS][32];

    const int lane = threadIdx.x & 63;
    const int w    = threadIdx.x >> 6;    // 0..7
    const int r = lane & 15, g14 = lane >> 4;
    const int b = blockIdx.y;
    const int seg0 = segbase + blockIdx.x * S;
    const int tog  = seg0 - TH;

    const float* hfb = hfin + (size_t)b * SEQ * RES_CH;
    const short* hbb = hbin + (size_t)b * SEQ * RES_CH;
    float* hfo = hfout + (size_t)b * SEQ * RES_CH;
    short* hbo = hbout + (size_t)b * SEQ * RES_CH;
    short* zbb = Z + (size_t)b * OUTLEN * QTOT;

    f32x4 carry[2][2];
    int Ht = hsum, pmt = pminIn;

#pragma unroll 1
    for (int t = 0; t < LC; ++t) {
        const int d = 1 << ((li0 + t) % 10);
        Ht -= d; pmt += d;
        const bool bglob = (t == 0);
        const bool last  = (t == LC - 1);
        const short* wAl = wAg + (li0 + t) * 4096;
        const short* wRl = wRg + (li0 + t) * 1024;
        const int liq = (li0 + t) * DIL_CH;
        char* tw = (char*)&tile[t & (NTB - 1)][0][0];
        const char* trd = (const char*)&tile[(t + NTB - 1) & (NTB - 1)][0][0];

        bf16x8 av[4][2];
#pragma unroll
        for (int fi = 0; fi < 4; ++fi)
#pragma unroll
            for (int kt = 0; kt < 2; ++kt)
                av[fi][kt] = *(const bf16x8*)(wAl + (fi * 16 + r) * 64 + kt * 32 + g14 * 8);
        bf16x8 avr[2];
#pragma unroll
        for (int fi = 0; fi < 2; ++fi)
            avr[fi] = *(const bf16x8*)(wRl + (fi * 16 + r) * 32 + g14 * 8);

        {
            const int cp0 = seg0 + w * 32;
            chunk_body<true>(cp0, bglob, last, d, tog, hbb, hfb, hfo, hbo,
                             zbb, liq, trd, tw, av, avr, &carry, r, g14);
        }
        int lo = seg0 - Ht; if (lo < pmt) lo = pmt;
        const int nh = (seg0 - lo + 31) >> 5;
#pragma unroll 1
        for (int hc = w; hc < nh; hc += 8) {
            const int cp0 = seg0 - (hc + 1) * 32;
            chunk_body<false>(cp0, bglob, last, d, tog, hbb, hfb, hfo, hbo,
                              zbb, liq, trd, tw, av, avr, nullptr, r, g14);
        }
        lgkm_barrier();   // << R11 change: no vmcnt(0) drain per layer
    }
}

// ---------------- skip GEMM: 8-phase counted-vmcnt (verbatim R9) -----------
__global__ __launch_bounds__(512, 1) void k_skip_8ph(
    const short* __restrict__ Z, const short* __restrict__ wskB,
    short* __restrict__ skipb)
{
    __shared__ short lds[2][32768];   // [parity][A:16384 shorts | B:16384]

    const int bid = blockIdx.x;       // 256 blocks
    const int b   = bid & 7;          // one batch per XCD
    const int sb  = (bid >> 3) & 1;
    const int pb  = bid >> 4;         // 0..15
    const int s0  = sb * 256;
    const int p0  = pb * 256;

    const int tid  = threadIdx.x;
    const int lane = tid & 63;
    const int w    = tid >> 6;        // 0..7
    const int wm   = w >> 2;          // 0..1 (s half)
    const int wn   = w & 3;           // 0..3 (p quarter)
    const int r = lane & 15, g = lane >> 4;

    const short* Ag = wskB + (size_t)s0 * QTOT;
    const short* Bg = Z + ((size_t)b * OUTLEN + p0) * QTOT;

    const int srow = tid >> 3;        // 0..63 (row within 64-row chunk)
    const int sblk = tid & 7;         // 16B block within 128B row

#define STG(PI, ISA, HH, KT)                                                  \
    {                                                                         \
        _Pragma("unroll") for (int j = 0; j < 2; ++j) {                       \
            int grow = (HH) * 128 + j * 64 + srow;                            \
            const short* gp = ((ISA) ? Ag : Bg) + (size_t)grow * QTOT         \
                              + (KT) * 64 + ((sblk ^ (grow & 7)) * 8);        \
            short* lp = &lds[PI][((ISA) ? 0 : 16384) +                        \
                                 ((HH) * 128 + j * 64 + w * 8) * 64];         \
            GLOAD_LDS16(gp, lp);                                              \
        }                                                                     \
    }

#define DS_A(dst, bufi, fi_, kk_)                                             \
    { int row_ = wm * 128 + (fi_) * 16 + r;                                   \
      dst = *(const bf16x8*)&lds[bufi][row_ * 64 + ((((kk_) * 4 + g) ^ (row_ & 7)) * 8)]; }
#define DS_B(dst, bufi, fj_, kk_)                                             \
    { int row_ = wn * 64 + (fj_) * 16 + r;                                    \
      dst = *(const bf16x8*)&lds[bufi][16384 + row_ * 64 + ((((kk_) * 4 + g) ^ (row_ & 7)) * 8)]; }

#define FENCE asm volatile("" ::: "memory")
#define VM4   asm volatile("s_waitcnt vmcnt(4)" ::: "memory")

#define PHASE(BUF, FIB, READB, STAGECODE, VMW)                                \
    {                                                                         \
        if (READB) {                                                          \
            _Pragma("unroll") for (int fj = 0; fj < 4; ++fj)                  \
                _Pragma("unroll") for (int kk = 0; kk < 2; ++kk)              \
                    DS_B(bv[fj][kk], BUF, fj, kk);                            \
        }                                                                     \
        bf16x8 a0k0, a0k1, a1k0, a1k1;                                        \
        DS_A(a0k0, BUF, FIB, 0); DS_A(a0k1, BUF, FIB, 1);                     \
        DS_A(a1k0, BUF, (FIB) + 1, 0); DS_A(a1k1, BUF, (FIB) + 1, 1);         \
        STAGECODE;                                                            \
        VMW;                                                                  \
        FENCE; __builtin_amdgcn_s_barrier(); FENCE;                           \
        __builtin_amdgcn_s_setprio(1);                                        \
        _Pragma("unroll") for (int fj = 0; fj < 4; ++fj) {                    \
            acc[FIB][fj] = __builtin_amdgcn_mfma_f32_16x16x32_bf16(           \
                a0k0, bv[fj][0], acc[FIB][fj], 0, 0, 0);                      \
            acc[FIB][fj] = __builtin_amdgcn_mfma_f32_16x16x32_bf16(           \
                a0k1, bv[fj][1], acc[FIB][fj], 0, 0, 0);                      \
            acc[(FIB) + 1][fj] = __builtin_amdgcn_mfma_f32_16x16x32_bf16(     \
                a1k0, bv[fj][0], acc[(FIB) + 1][fj], 0, 0, 0);                \
            acc[(FIB) + 1][fj] = __builtin_amdgcn_mfma_f32_16x16x32_bf16(     \
                a1k1, bv[fj][1], acc[(FIB) + 1][fj], 0, 0, 0);                \
        }                                                                     \
        __builtin_amdgcn_s_setprio(0);                                        \
        FENCE; __builtin_amdgcn_s_barrier(); FENCE;                           \
    }

    f32x4 acc[8][4];
    const f32x4 zero4 = {0.f, 0.f, 0.f, 0.f};
#pragma unroll
    for (int fi = 0; fi < 8; ++fi)
#pragma unroll
        for (int fj = 0; fj < 4; ++fj) acc[fi][fj] = zero4;

    bf16x8 bv[4][2];

    STG(0, 1, 0, 0) STG(0, 1, 1, 0) STG(0, 0, 0, 0) STG(0, 0, 1, 0)
    STG(1, 0, 0, 1) STG(1, 0, 1, 1)
    VM4;
    FENCE; __builtin_amdgcn_s_barrier(); FENCE;

    const int NIT = QTOT / 128;       // 10 iterations (2 K-tiles each)
#pragma unroll 1
    for (int i = 0; i < NIT; ++i) {
        const int k1 = 2 * i + 1;
        const int k2 = 2 * i + 2, k3 = 2 * i + 3;
        const bool more = (i + 1 < NIT);
        PHASE(0, 0, 1, STG(1, 1, 0, k1), )                       // ph0
        PHASE(0, 2, 0, STG(1, 1, 1, k1), )                       // ph1
        PHASE(0, 4, 0, if (more) STG(0, 0, 0, k2), )             // ph2
        PHASE(0, 6, 0, if (more) STG(0, 0, 1, k2), VM4)          // ph3
        PHASE(1, 0, 1, if (more) STG(0, 1, 0, k2), )             // ph4
        PHASE(1, 2, 0, if (more) STG(0, 1, 1, k2), )             // ph5
        PHASE(1, 4, 0, if (more) STG(1, 0, 0, k3), )             // ph6
        PHASE(1, 6, 0, if (more) STG(1, 0, 1, k3), VM4)          // ph7
    }

    short* skb = skipb + (size_t)b * OUTLEN * SKIP_CH;
#pragma unroll
    for (int fj = 0; fj < 4; ++fj) {
        int p = p0 + wn * 64 + fj * 16 + r;
#pragma unroll
        for (int fi = 0; fi < 8; ++fi) {
            int s = s0 + wm * 128 + fi * 16 + g * 4;
            short4_t v;
#pragma unroll
            for (int e = 0; e < 4; ++e) v[e] = f2bf(fmaxf(acc[fi][fj][e], 0.f));
            *(short4_t*)(skb + (size_t)p * SKIP_CH + s) = v;
        }
    }
#undef PHASE
#undef STG
#undef DS_A
#undef DS_B
}

// ---------------- end GEMM (m97 structure, verbatim R9) ----------------
#define EK_STAGE(bf, kt)                                                      \
    {                                                                         \
        _Pragma("unroll") for (int j = 0; j < 2; ++j) {                       \
            const short* ga = Ab + (size_t)(rb + j * 16 + l4) * SKIP_CH       \
                                 + (kt) * 32 + csw * 8;                       \
            GLOAD_LDS16(ga, &At[bf][(rb + j * 16) * 32]);                     \
            const short* gb = Bb + (size_t)(rb + j * 16 + l4) * SKIP_CH       \
                                 + (kt) * 32 + csw * 8;                       \
            GLOAD_LDS16(gb, &Bt[bf][(rb + j * 16) * 32]);                     \
        }                                                                     \
    }

__global__ __launch_bounds__(256) void k_end_m97(
    const short* __restrict__ skipB, const short* __restrict__ ewB,
    const float* __restrict__ eb, float* __restrict__ out)
{
    __shared__ short At[2][128 * 32];
    __shared__ short Bt[2][128 * 32];

    const int bid = blockIdx.x;          // 512 blocks
    const int b    = bid & 7;
    const int rest = bid >> 3;
    const int cb   = rest & 1;
    const int pb   = rest >> 1;
    const int c0   = cb * 128;
    const int p0   = pb * 128;

    const int lane = threadIdx.x & 63;
    const int w    = threadIdx.x >> 6;
    const int r = lane & 15, g14 = lane >> 4;
    const int soff = (w >> 1) * 64;
    const int poff = (w & 1) * 64;

    const short* Ab = ewB + (size_t)c0 * SKIP_CH;
    const short* Bb = skipB + ((size_t)b * OUTLEN + p0) * SKIP_CH;

    const int rb = w * 32;
    const int l4 = lane >> 2;
    const int c4 = lane & 3;
    const int csw = c4 ^ ((l4 >> 1) & 3);
    const int rsw = (g14 ^ ((r >> 1) & 3)) * 8;

    f32x4 acc[4][4];
    const f32x4 zero4 = {0.f, 0.f, 0.f, 0.f};
#pragma unroll
    for (int fi = 0; fi < 4; ++fi)
#pragma unroll
        for (int fj = 0; fj < 4; ++fj) acc[fi][fj] = zero4;

    EK_STAGE(0, 0)
    __syncthreads();

    int cur = 0;
#pragma unroll 1
    for (int kt = 0; kt < SKIP_CH / 32; ++kt) {
        if (kt + 1 < SKIP_CH / 32) EK_STAGE(cur ^ 1, kt + 1)

        bf16x8 av[4], bv[4];
#pragma unroll
        for (int fi = 0; fi < 4; ++fi)
            av[fi] = *(const bf16x8*)&At[cur][(soff + fi * 16 + r) * 32 + rsw];
#pragma unroll
        for (int fj = 0; fj < 4; ++fj)
            bv[fj] = *(const bf16x8*)&Bt[cur][(poff + fj * 16 + r) * 32 + rsw];

#pragma unroll
        for (int fi = 0; fi < 4; ++fi)
#pragma unroll
            for (int fj = 0; fj < 4; ++fj)
                acc[fi][fj] = __builtin_amdgcn_mfma_f32_16x16x32_bf16(
                    av[fi], bv[fj], acc[fi][fj], 0, 0, 0);

        __syncthreads();
        cur ^= 1;
    }

#pragma unroll
    for (int fj = 0; fj < 4; ++fj) {
        int p = p0 + poff + fj * 16 + r;
#pragma unroll
        for (int fi = 0; fi < 4; ++fi) {
            int cls = c0 + soff + fi * 16 + g14 * 4;
            f32x4 bias = *(const f32x4*)(eb + cls);
            f32x4 v;
#pragma unroll
            for (int e = 0; e < 4; ++e) v[e] = acc[fi][fj][e] + bias[e];
            *(f32x4*)(out + ((size_t)b * OUTLEN + p) * CLASSES + cls) = v;
        }
    }
}

extern "C" void kernel_launch(void* const* d_in, const int* in_sizes, int n_in,
                              void* d_out, int out_size, void* d_ws, size_t ws_size,
                              hipStream_t stream) {
    const float* x   = (const float*)d_in[0];
    const float* sw  = (const float*)d_in[1];
    const float* fw  = (const float*)d_in[2];
    const float* gw  = (const float*)d_in[3];
    const float* rw  = (const float*)d_in[4];
    const float* wsk = (const float*)d_in[5];
    const float* ew  = (const float*)d_in[6];
    const float* eb  = (const float*)d_in[7];
    float* out = (float*)d_out;

    const size_t HN = (size_t)BATCH * SEQ * RES_CH;
    float* hf0 = (float*)d_ws;
    float* hf1 = hf0 + HN;
    short* hb0 = (short*)(hf1 + HN);
    short* hb1 = hb0 + HN;
    short* Z     = hb1 + HN;
    short* skipb = Z + (size_t)BATCH * OUTLEN * QTOT;
    short* wA    = skipb + (size_t)BATCH * OUTLEN * SKIP_CH;
    short* wR    = wA + NLAYERS * 64 * 64;
    short* wskB  = wR + NLAYERS * 32 * 32;
    short* ewB   = wskB + (size_t)SKIP_CH * QTOT;

    k_prep<<<dim3(1024), 256, 0, stream>>>(x, sw, fw, gw, rw, wsk, ew,
                                           hf0, hb0, wA, wR, wskB, ewB);

    float* hf[2] = {hf0, hf1};
    short* hb[2] = {hb0, hb1};
    int cur = 0, pmin = 0;
    for (int dec = 0; dec < 4; ++dec) {
        int li0 = dec * 10;
        // group 1: d = 1..128 (8 layers), halo sum 255, S=256
        int segbase = pmin + 255;
        int nseg = (SEQ - segbase + 255) / 256;
        k_fused8<8, 256, 288, 2><<<dim3(nseg, BATCH), 512, 0, stream>>>(
            hf[cur], hb[cur], hf[cur ^ 1], hb[cur ^ 1], wA, wR, Z,
            li0, pmin, 255, segbase);
        cur ^= 1; pmin = segbase;
        // group 2: d = 256, 512 (2 layers), halo sum 768, S=256
        segbase = pmin + 768;
        nseg = (SEQ - segbase + 255) / 256;
        k_fused8<2, 256, 512, 1><<<dim3(nseg, BATCH), 512, 0, stream>>>(
            hf[cur], hb[cur], hf[cur ^ 1], hb[cur ^ 1], wA, wR, Z,
            li0 + 8, pmin, 768, segbase);
        cur ^= 1; pmin = segbase;
    }

    k_skip_8ph<<<dim3(256), 512, 0, stream>>>(Z, wskB, skipb);
    k_end_m97<<<dim3(512), 256, 0, stream>>>(skipb, ewB, eb, out);
}

// Round 12
// 296.232 us; speedup vs baseline: 1.1826x; 1.0289x over previous
//
#include <hip/hip_runtime.h>
#include <hip/hip_bf16.h>

// WaveNet on MI355X — round 12: R11 structure (304us) + layer critical-path
// surgery: (1) cross-layer weight prefetch (t+1 wA/wR loads issued during
// layer t's halo compute), (2) s_setprio(1) around MFMA clusters,
// (3) coalesced wskB transpose in prep. Skip/end verbatim.
//
// Layouts (p = original position in [0,8192)):
//   hf0/hf1 : [b][p][c] f32   residual stream (double-buffered per group)
//   hb0/hb1 : [b][p][c] bf16  shadow of hf (MFMA B-operand / taps)
//   Z       : [b][p4][q] bf16, q = layer*32+o
//   skipb   : [b][p4][s] bf16 (relu applied)
//   wA      : [40][64 rows][64 k] bf16 (permuted rows: D-frag == B-frag trick)
//   wR      : [40][32 c][32 o] bf16
//   wskB    : [512 s][1280 q] bf16
//   ewB     : [256 cls][512 s] bf16

#define BATCH   8
#define SEQ     8192
#define RES_CH  32
#define DIL_CH  32
#define SKIP_CH 512
#define CLASSES 256
#define NLAYERS 40
#define OUTLEN  4096
#define PSTART  (SEQ - OUTLEN)      // 4096
#define QTOT    (NLAYERS * DIL_CH)  // 1280

typedef __attribute__((ext_vector_type(8))) short bf16x8;
typedef __attribute__((ext_vector_type(4))) short short4_t;
typedef __attribute__((ext_vector_type(4))) float f32x4;

// f32 -> bf16 (RNE) via hardware cvt
__device__ __forceinline__ short f2bf(float x) {
    __bf16 b = (__bf16)x;
    return __builtin_bit_cast(short, b);
}
__device__ __forceinline__ float bf2f(short s) {
    return __uint_as_float(((unsigned)(unsigned short)s) << 16);
}
__device__ __forceinline__ float zact(float f, float g) {
    float a = __expf(fminf(-2.0f * f, 80.0f));
    float b = __expf(fminf(-g, 80.0f));
    return (1.0f - a) * __builtin_amdgcn_rcpf((1.0f + a) * (1.0f + b));
}
// layer-tile byte-offset swizzle (rows of 64B)
__device__ __forceinline__ int tswz(int row, int cb) {
    return row * 64 + (cb ^ (((row & 3) << 4) | ((row & 4) << 3)));
}
// barrier ordering LDS only: no vmcnt(0) drain of global stores
__device__ __forceinline__ void lgkm_barrier() {
    asm volatile("s_waitcnt lgkmcnt(0)\n\ts_barrier" ::: "memory");
}

#define GLOAD_LDS16(g, l)                                                    \
    __builtin_amdgcn_global_load_lds(                                        \
        (const __attribute__((address_space(1))) unsigned int*)(g),          \
        (__attribute__((address_space(3))) unsigned int*)(l), 16, 0, 0)

// ---------------- prep ----------------
__global__ __launch_bounds__(256) void k_prep(
    const float* __restrict__ x, const float* __restrict__ sw,
    const float* __restrict__ fw, const float* __restrict__ gw,
    const float* __restrict__ rw, const float* __restrict__ wsk,
    const float* __restrict__ ew,
    float* __restrict__ hf, short* __restrict__ hb,
    short* __restrict__ wA, short* __restrict__ wR,
    short* __restrict__ wskB, short* __restrict__ ewB)
{
    const int gt = blockIdx.x * 256 + threadIdx.x;
    const int gn = gridDim.x * 256;
    for (int idx = gt; idx < BATCH * SEQ; idx += gn) {
        float v = x[idx];
        float* hp = hf + (size_t)idx * RES_CH;
        short* bp = hb + (size_t)idx * RES_CH;
#pragma unroll
        for (int c = 0; c < RES_CH; ++c) {
            float t = v * sw[c];
            hp[c] = t;
            bp[c] = f2bf(t);
        }
    }
    for (int idx = gt; idx < NLAYERS * 64 * 64; idx += gn) {
        int k = idx & 63, rho = (idx >> 6) & 63, i = idx >> 12;
        int tap = k >> 5, c = k & 31;
        int fgsel = rho >> 5, rr = rho & 31;
        int fp = rr >> 4, gg = (rr >> 2) & 3, e = rr & 3;
        int o = gg * 8 + fp * 4 + e;
        float v = fgsel ? gw[((i * 32 + o) * 32 + c) * 2 + tap]
                        : fw[((i * 32 + o) * 32 + c) * 2 + tap];
        wA[idx] = f2bf(v);
    }
    for (int idx = gt; idx < NLAYERS * 1024; idx += gn)
        wR[idx] = f2bf(rw[idx]);
    // coalesced transpose: read wsk in natural order [i][s][o], write
    // 64B-contiguous o-chunks into wskB[s][i*32+o]
    for (int idx = gt; idx < NLAYERS * SKIP_CH * DIL_CH; idx += gn) {
        int o = idx & 31;
        int s = (idx >> 5) & (SKIP_CH - 1);
        int i = idx >> 14;                  // 512*32 = 16384
        wskB[(size_t)s * QTOT + i * 32 + o] = f2bf(wsk[idx]);
    }
    for (int idx = gt; idx < CLASSES * SKIP_CH; idx += gn)
        ewB[idx] = f2bf(ew[idx]);
}

// ---------------- fused layer-group kernel ----------------
template<bool OWNED>
__device__ __forceinline__ void chunk_body(
    int cp0, bool bglob, bool last, int d, int tog,
    const short* __restrict__ hbb, const float* __restrict__ hfb,
    float* __restrict__ hfo, short* __restrict__ hbo,
    short* __restrict__ zbb, int liq,
    const char* trd, char* tw,
    const bf16x8 (&av)[4][2], const bf16x8 (&avr)[2],
    f32x4 (*carryc)[2][2],
    int r, int g14)
{
    int pl[2]; bool pv[2];
#pragma unroll
    for (int fj = 0; fj < 2; ++fj) {
        int p = cp0 + fj * 16 + r;
        pv[fj] = p < SEQ;
        pl[fj] = pv[fj] ? p : SEQ - 1;
    }

    bf16x8 bv[2][2];
    if (bglob) {
#pragma unroll
        for (int fj = 0; fj < 2; ++fj) {
            bv[fj][0] = *(const bf16x8*)(hbb + (pl[fj] - d) * 32 + g14 * 8);
            bv[fj][1] = *(const bf16x8*)(hbb + pl[fj] * 32 + g14 * 8);
        }
    } else {
#pragma unroll
        for (int fj = 0; fj < 2; ++fj) {
            int tr = pl[fj] - tog;
            bv[fj][0] = *(const bf16x8*)(trd + tswz(tr - d, g14 * 16));
            bv[fj][1] = *(const bf16x8*)(trd + tswz(tr, g14 * 16));
        }
    }

    const f32x4 zero4 = {0.f, 0.f, 0.f, 0.f};
    f32x4 acc[4][2];
#pragma unroll
    for (int fi = 0; fi < 4; ++fi)
#pragma unroll
        for (int fj = 0; fj < 2; ++fj) acc[fi][fj] = zero4;

    __builtin_amdgcn_s_setprio(1);
#pragma unroll
    for (int kt = 0; kt < 2; ++kt)
#pragma unroll
        for (int fi = 0; fi < 4; ++fi)
#pragma unroll
            for (int fj = 0; fj < 2; ++fj)
                acc[fi][fj] = __builtin_amdgcn_mfma_f32_16x16x32_bf16(
                    av[fi][kt], bv[fj][kt], acc[fi][fj], 0, 0, 0);
    __builtin_amdgcn_s_setprio(0);

    bf16x8 zv8[2];
#pragma unroll
    for (int fj = 0; fj < 2; ++fj)
#pragma unroll
        for (int fp = 0; fp < 2; ++fp)
#pragma unroll
            for (int e = 0; e < 4; ++e)
                zv8[fj][fp * 4 + e] =
                    f2bf(zact(acc[fp][fj][e], acc[fp + 2][fj][e]));

    if constexpr (OWNED) {
#pragma unroll
        for (int fj = 0; fj < 2; ++fj)
            if (pv[fj] && pl[fj] >= PSTART) {
                short* zp = zbb + (size_t)(pl[fj] - PSTART) * QTOT + liq;
                *(bf16x8*)(zp + g14 * 8) = zv8[fj];
            }
    }

    f32x4 racc[2][2];
    if constexpr (OWNED) {
        if (bglob) {
#pragma unroll
            for (int fi = 0; fi < 2; ++fi)
#pragma unroll
                for (int fj = 0; fj < 2; ++fj)
                    racc[fi][fj] = *(const f32x4*)(hfb + pl[fj] * 32 + fi * 16 + g14 * 4);
        } else {
#pragma unroll
            for (int fi = 0; fi < 2; ++fi)
#pragma unroll
                for (int fj = 0; fj < 2; ++fj)
                    racc[fi][fj] = (*carryc)[fi][fj];
        }
    } else {
#pragma unroll
        for (int fj = 0; fj < 2; ++fj)
#pragma unroll
            for (int fi = 0; fi < 2; ++fi) {
                short4_t hv;
                if (bglob)
                    hv = *(const short4_t*)(hbb + pl[fj] * 32 + fi * 16 + g14 * 4);
                else
                    hv = *(const short4_t*)(trd + tswz(pl[fj] - tog, fi * 32 + g14 * 8));
                f32x4 cv;
#pragma unroll
                for (int e = 0; e < 4; ++e) cv[e] = bf2f(hv[e]);
                racc[fi][fj] = cv;
            }
    }

    __builtin_amdgcn_s_setprio(1);
#pragma unroll
    for (int fi = 0; fi < 2; ++fi)
#pragma unroll
        for (int fj = 0; fj < 2; ++fj)
            racc[fi][fj] = __builtin_amdgcn_mfma_f32_16x16x32_bf16(
                avr[fi], zv8[fj], racc[fi][fj], 0, 0, 0);
    __builtin_amdgcn_s_setprio(0);

    if constexpr (OWNED) {
#pragma unroll
        for (int fi = 0; fi < 2; ++fi)
#pragma unroll
            for (int fj = 0; fj < 2; ++fj)
                (*carryc)[fi][fj] = racc[fi][fj];
    }

    if (!last) {
#pragma unroll
        for (int fj = 0; fj < 2; ++fj)
            if (pv[fj]) {
                int tr = pl[fj] - tog;
#pragma unroll
                for (int fi = 0; fi < 2; ++fi) {
                    short4_t sv;
#pragma unroll
                    for (int e = 0; e < 4; ++e) sv[e] = f2bf(racc[fi][fj][e]);
                    *(short4_t*)(tw + tswz(tr, fi * 32 + g14 * 8)) = sv;
                }
            }
    } else {
        if constexpr (OWNED) {
#pragma unroll
            for (int fj = 0; fj < 2; ++fj)
                if (pv[fj]) {
#pragma unroll
                    for (int fi = 0; fi < 2; ++fi) {
                        *(f32x4*)(hfo + pl[fj] * 32 + fi * 16 + g14 * 4) = racc[fi][fj];
                        short4_t sv;
#pragma unroll
                        for (int e = 0; e < 4; ++e) sv[e] = f2bf(racc[fi][fj][e]);
                        *(short4_t*)(hbo + pl[fj] * 32 + fi * 16 + g14 * 4) = sv;
                    }
                }
        }
    }
}

template<int LC, int S, int TH, int NTB>
__global__ __launch_bounds__(512, 2) void k_fused8(
    const float* __restrict__ hfin, const short* __restrict__ hbin,
    float* __restrict__ hfout, short* __restrict__ hbout,
    const short* __restrict__ wAg, const short* __restrict__ wRg,
    short* __restrict__ Z, int li0, int pminIn, int hsum, int segbase)
{
    constexpr int TROWS = TH + S;
    __shared__ short tile[NTB][TROWS][32];

    const int lane = threadIdx.x & 63;
    const int w    = threadIdx.x >> 6;    // 0..7
    const int r = lane & 15, g14 = lane >> 4;
    const int b = blockIdx.y;
    const int seg0 = segbase + blockIdx.x * S;
    const int tog  = seg0 - TH;

    const float* hfb = hfin + (size_t)b * SEQ * RES_CH;
    const short* hbb = hbin + (size_t)b * SEQ * RES_CH;
    float* hfo = hfout + (size_t)b * SEQ * RES_CH;
    short* hbo = hbout + (size_t)b * SEQ * RES_CH;
    short* zbb = Z + (size_t)b * OUTLEN * QTOT;

    f32x4 carry[2][2];
    int Ht = hsum, pmt = pminIn;

    // prefetch layer li0's weights
    bf16x8 avN[4][2], avrN[2];
    {
        const short* wAl = wAg + li0 * 4096;
        const short* wRl = wRg + li0 * 1024;
#pragma unroll
        for (int fi = 0; fi < 4; ++fi)
#pragma unroll
            for (int kt = 0; kt < 2; ++kt)
                avN[fi][kt] = *(const bf16x8*)(wAl + (fi * 16 + r) * 64 + kt * 32 + g14 * 8);
#pragma unroll
        for (int fi = 0; fi < 2; ++fi)
            avrN[fi] = *(const bf16x8*)(wRl + (fi * 16 + r) * 32 + g14 * 8);
    }

#pragma unroll 1
    for (int t = 0; t < LC; ++t) {
        const int d = 1 << ((li0 + t) % 10);
        Ht -= d; pmt += d;
        const bool bglob = (t == 0);
        const bool last  = (t == LC - 1);
        const int liq = (li0 + t) * DIL_CH;
        char* tw = (char*)&tile[t & (NTB - 1)][0][0];
        const char* trd = (const char*)&tile[(t + NTB - 1) & (NTB - 1)][0][0];

        // consume prefetched weights for this layer
        bf16x8 av[4][2], avr[2];
#pragma unroll
        for (int fi = 0; fi < 4; ++fi)
#pragma unroll
            for (int kt = 0; kt < 2; ++kt)
                av[fi][kt] = avN[fi][kt];
#pragma unroll
        for (int fi = 0; fi < 2; ++fi)
            avr[fi] = avrN[fi];

        // owned chunk
        {
            const int cp0 = seg0 + w * 32;
            chunk_body<true>(cp0, bglob, last, d, tog, hbb, hfb, hfo, hbo,
                             zbb, liq, trd, tw, av, avr, &carry, r, g14);
        }

        // issue next layer's weight prefetch (flies during halo + barrier)
        if (t + 1 < LC) {
            const short* wAn = wAg + (li0 + t + 1) * 4096;
            const short* wRn = wRg + (li0 + t + 1) * 1024;
#pragma unroll
            for (int fi = 0; fi < 4; ++fi)
#pragma unroll
                for (int kt = 0; kt < 2; ++kt)
                    avN[fi][kt] = *(const bf16x8*)(wAn + (fi * 16 + r) * 64 + kt * 32 + g14 * 8);
#pragma unroll
            for (int fi = 0; fi < 2; ++fi)
                avrN[fi] = *(const bf16x8*)(wRn + (fi * 16 + r) * 32 + g14 * 8);
        }

        // halo chunks (left of seg0), split across all 8 waves
        int lo = seg0 - Ht; if (lo < pmt) lo = pmt;
        const int nh = (seg0 - lo + 31) >> 5;
#pragma unroll 1
        for (int hc = w; hc < nh; hc += 8) {
            const int cp0 = seg0 - (hc + 1) * 32;
            chunk_body<false>(cp0, bglob, last, d, tog, hbb, hfb, hfo, hbo,
                              zbb, liq, trd, tw, av, avr, nullptr, r, g14);
        }
        lgkm_barrier();
    }
}

// ---------------- skip GEMM: 8-phase counted-vmcnt (verbatim R9) -----------
__global__ __launch_bounds__(512, 1) void k_skip_8ph(
    const short* __restrict__ Z, const short* __restrict__ wskB,
    short* __restrict__ skipb)
{
    __shared__ short lds[2][32768];   // [parity][A:16384 shorts | B:16384]

    const int bid = blockIdx.x;       // 256 blocks
    const int b   = bid & 7;          // one batch per XCD
    const int sb  = (bid >> 3) & 1;
    const int pb  = bid >> 4;         // 0..15
    const int s0  = sb * 256;
    const int p0  = pb * 256;

    const int tid  = threadIdx.x;
    const int lane = tid & 63;
    const int w    = tid >> 6;        // 0..7
    const int wm   = w >> 2;          // 0..1 (s half)
    const int wn   = w & 3;           // 0..3 (p quarter)
    const int r = lane & 15, g = lane >> 4;

    const short* Ag = wskB + (size_t)s0 * QTOT;
    const short* Bg = Z + ((size_t)b * OUTLEN + p0) * QTOT;

    const int srow = tid >> 3;        // 0..63 (row within 64-row chunk)
    const int sblk = tid & 7;         // 16B block within 128B row

#define STG(PI, ISA, HH, KT)                                                  \
    {                                                                         \
        _Pragma("unroll") for (int j = 0; j < 2; ++j) {                       \
            int grow = (HH) * 128 + j * 64 + srow;                            \
            const short* gp = ((ISA) ? Ag : Bg) + (size_t)grow * QTOT         \
                              + (KT) * 64 + ((sblk ^ (grow & 7)) * 8);        \
            short* lp = &lds[PI][((ISA) ? 0 : 16384) +                        \
                                 ((HH) * 128 + j * 64 + w * 8) * 64];         \
            GLOAD_LDS16(gp, lp);                                              \
        }                                                                     \
    }

#define DS_A(dst, bufi, fi_, kk_)                                             \
    { int row_ = wm * 128 + (fi_) * 16 + r;                                   \
      dst = *(const bf16x8*)&lds[bufi][row_ * 64 + ((((kk_) * 4 + g) ^ (row_ & 7)) * 8)]; }
#define DS_B(dst, bufi, fj_, kk_)                                             \
    { int row_ = wn * 64 + (fj_) * 16 + r;                                    \
      dst = *(const bf16x8*)&lds[bufi][16384 + row_ * 64 + ((((kk_) * 4 + g) ^ (row_ & 7)) * 8)]; }

#define FENCE asm volatile("" ::: "memory")
#define VM4   asm volatile("s_waitcnt vmcnt(4)" ::: "memory")

#define PHASE(BUF, FIB, READB, STAGECODE, VMW)                                \
    {                                                                         \
        if (READB) {                                                          \
            _Pragma("unroll") for (int fj = 0; fj < 4; ++fj)                  \
                _Pragma("unroll") for (int kk = 0; kk < 2; ++kk)              \
                    DS_B(bv[fj][kk], BUF, fj, kk);                            \
        }                                                                     \
        bf16x8 a0k0, a0k1, a1k0, a1k1;                                        \
        DS_A(a0k0, BUF, FIB, 0); DS_A(a0k1, BUF, FIB, 1);                     \
        DS_A(a1k0, BUF, (FIB) + 1, 0); DS_A(a1k1, BUF, (FIB) + 1, 1);         \
        STAGECODE;                                                            \
        VMW;                                                                  \
        FENCE; __builtin_amdgcn_s_barrier(); FENCE;                           \
        __builtin_amdgcn_s_setprio(1);                                        \
        _Pragma("unroll") for (int fj = 0; fj < 4; ++fj) {                    \
            acc[FIB][fj] = __builtin_amdgcn_mfma_f32_16x16x32_bf16(           \
                a0k0, bv[fj][0], acc[FIB][fj], 0, 0, 0);                      \
            acc[FIB][fj] = __builtin_amdgcn_mfma_f32_16x16x32_bf16(           \
                a0k1, bv[fj][1], acc[FIB][fj], 0, 0, 0);                      \
            acc[(FIB) + 1][fj] = __builtin_amdgcn_mfma_f32_16x16x32_bf16(     \
                a1k0, bv[fj][0], acc[(FIB) + 1][fj], 0, 0, 0);                \
            acc[(FIB) + 1][fj] = __builtin_amdgcn_mfma_f32_16x16x32_bf16(     \
                a1k1, bv[fj][1], acc[(FIB) + 1][fj], 0, 0, 0);                \
        }                                                                     \
        __builtin_amdgcn_s_setprio(0);                                        \
        FENCE; __builtin_amdgcn_s_barrier(); FENCE;                           \
    }

    f32x4 acc[8][4];
    const f32x4 zero4 = {0.f, 0.f, 0.f, 0.f};
#pragma unroll
    for (int fi = 0; fi < 8; ++fi)
#pragma unroll
        for (int fj = 0; fj < 4; ++fj) acc[fi][fj] = zero4;

    bf16x8 bv[4][2];

    STG(0, 1, 0, 0) STG(0, 1, 1, 0) STG(0, 0, 0, 0) STG(0, 0, 1, 0)
    STG(1, 0, 0, 1) STG(1, 0, 1, 1)
    VM4;
    FENCE; __builtin_amdgcn_s_barrier(); FENCE;

    const int NIT = QTOT / 128;       // 10 iterations (2 K-tiles each)
#pragma unroll 1
    for (int i = 0; i < NIT; ++i) {
        const int k1 = 2 * i + 1;
        const int k2 = 2 * i + 2, k3 = 2 * i + 3;
        const bool more = (i + 1 < NIT);
        PHASE(0, 0, 1, STG(1, 1, 0, k1), )                       // ph0
        PHASE(0, 2, 0, STG(1, 1, 1, k1), )                       // ph1
        PHASE(0, 4, 0, if (more) STG(0, 0, 0, k2), )             // ph2
        PHASE(0, 6, 0, if (more) STG(0, 0, 1, k2), VM4)          // ph3
        PHASE(1, 0, 1, if (more) STG(0, 1, 0, k2), )             // ph4
        PHASE(1, 2, 0, if (more) STG(0, 1, 1, k2), )             // ph5
        PHASE(1, 4, 0, if (more) STG(1, 0, 0, k3), )             // ph6
        PHASE(1, 6, 0, if (more) STG(1, 0, 1, k3), VM4)          // ph7
    }

    short* skb = skipb + (size_t)b * OUTLEN * SKIP_CH;
#pragma unroll
    for (int fj = 0; fj < 4; ++fj) {
        int p = p0 + wn * 64 + fj * 16 + r;
#pragma unroll
        for (int fi = 0; fi < 8; ++fi) {
            int s = s0 + wm * 128 + fi * 16 + g * 4;
            short4_t v;
#pragma unroll
            for (int e = 0; e < 4; ++e) v[e] = f2bf(fmaxf(acc[fi][fj][e], 0.f));
            *(short4_t*)(skb + (size_t)p * SKIP_CH + s) = v;
        }
    }
#undef PHASE
#undef STG
#undef DS_A
#undef DS_B
}

// ---------------- end GEMM (m97 structure, verbatim R9) ----------------
#define EK_STAGE(bf, kt)                                                      \
    {                                                                         \
        _Pragma("unroll") for (int j = 0; j < 2; ++j) {                       \
            const short* ga = Ab + (size_t)(rb + j * 16 + l4) * SKIP_CH       \
                                 + (kt) * 32 + csw * 8;                       \
            GLOAD_LDS16(ga, &At[bf][(rb + j * 16) * 32]);                     \
            const short* gb = Bb + (size_t)(rb + j * 16 + l4) * SKIP_CH       \
                                 + (kt) * 32 + csw * 8;                       \
            GLOAD_LDS16(gb, &Bt[bf][(rb + j * 16) * 32]);                     \
        }                                                                     \
    }

__global__ __launch_bounds__(256) void k_end_m97(
    const short* __restrict__ skipB, const short* __restrict__ ewB,
    const float* __restrict__ eb, float* __restrict__ out)
{
    __shared__ short At[2][128 * 32];
    __shared__ short Bt[2][128 * 32];

    const int bid = blockIdx.x;          // 512 blocks
    const int b    = bid & 7;
    const int rest = bid >> 3;
    const int cb   = rest & 1;
    const int pb   = rest >> 1;
    const int c0   = cb * 128;
    const int p0   = pb * 128;

    const int lane = threadIdx.x & 63;
    const int w    = threadIdx.x >> 6;
    const int r = lane & 15, g14 = lane >> 4;
    const int soff = (w >> 1) * 64;
    const int poff = (w & 1) * 64;

    const short* Ab = ewB + (size_t)c0 * SKIP_CH;
    const short* Bb = skipB + ((size_t)b * OUTLEN + p0) * SKIP_CH;

    const int rb = w * 32;
    const int l4 = lane >> 2;
    const int c4 = lane & 3;
    const int csw = c4 ^ ((l4 >> 1) & 3);
    const int rsw = (g14 ^ ((r >> 1) & 3)) * 8;

    f32x4 acc[4][4];
    const f32x4 zero4 = {0.f, 0.f, 0.f, 0.f};
#pragma unroll
    for (int fi = 0; fi < 4; ++fi)
#pragma unroll
        for (int fj = 0; fj < 4; ++fj) acc[fi][fj] = zero4;

    EK_STAGE(0, 0)
    __syncthreads();

    int cur = 0;
#pragma unroll 1
    for (int kt = 0; kt < SKIP_CH / 32; ++kt) {
        if (kt + 1 < SKIP_CH / 32) EK_STAGE(cur ^ 1, kt + 1)

        bf16x8 av[4], bv[4];
#pragma unroll
        for (int fi = 0; fi < 4; ++fi)
            av[fi] = *(const bf16x8*)&At[cur][(soff + fi * 16 + r) * 32 + rsw];
#pragma unroll
        for (int fj = 0; fj < 4; ++fj)
            bv[fj] = *(const bf16x8*)&Bt[cur][(poff + fj * 16 + r) * 32 + rsw];

#pragma unroll
        for (int fi = 0; fi < 4; ++fi)
#pragma unroll
            for (int fj = 0; fj < 4; ++fj)
                acc[fi][fj] = __builtin_amdgcn_mfma_f32_16x16x32_bf16(
                    av[fi], bv[fj], acc[fi][fj], 0, 0, 0);

        __syncthreads();
        cur ^= 1;
    }

#pragma unroll
    for (int fj = 0; fj < 4; ++fj) {
        int p = p0 + poff + fj * 16 + r;
#pragma unroll
        for (int fi = 0; fi < 4; ++fi) {
            int cls = c0 + soff + fi * 16 + g14 * 4;
            f32x4 bias = *(const f32x4*)(eb + cls);
            f32x4 v;
#pragma unroll
            for (int e = 0; e < 4; ++e) v[e] = acc[fi][fj][e] + bias[e];
            *(f32x4*)(out + ((size_t)b * OUTLEN + p) * CLASSES + cls) = v;
        }
    }
}

extern "C" void kernel_launch(void* const* d_in, const int* in_sizes, int n_in,
                              void* d_out, int out_size, void* d_ws, size_t ws_size,
                              hipStream_t stream) {
    const float* x   = (const float*)d_in[0];
    const float* sw  = (const float*)d_in[1];
    const float* fw  = (const float*)d_in[2];
    const float* gw  = (const float*)d_in[3];
    const float* rw  = (const float*)d_in[4];
    const float* wsk = (const float*)d_in[5];
    const float* ew  = (const float*)d_in[6];
    const float* eb  = (const float*)d_in[7];
    float* out = (float*)d_out;

    const size_t HN = (size_t)BATCH * SEQ * RES_CH;
    float* hf0 = (float*)d_ws;
    float* hf1 = hf0 + HN;
    short* hb0 = (short*)(hf1 + HN);
    short* hb1 = hb0 + HN;
    short* Z     = hb1 + HN;
    short* skipb = Z + (size_t)BATCH * OUTLEN * QTOT;
    short* wA    = skipb + (size_t)BATCH * OUTLEN * SKIP_CH;
    short* wR    = wA + NLAYERS * 64 * 64;
    short* wskB  = wR + NLAYERS * 32 * 32;
    short* ewB   = wskB + (size_t)SKIP_CH * QTOT;

    k_prep<<<dim3(1024), 256, 0, stream>>>(x, sw, fw, gw, rw, wsk, ew,
                                           hf0, hb0, wA, wR, wskB, ewB);

    float* hf[2] = {hf0, hf1};
    short* hb[2] = {hb0, hb1};
    int cur = 0, pmin = 0;
    for (int dec = 0; dec < 4; ++dec) {
        int li0 = dec * 10;
        // group 1: d = 1..128 (8 layers), halo sum 255, S=256
        int segbase = pmin + 255;
        int nseg = (SEQ - segbase + 255) / 256;
        k_fused8<8, 256, 288, 2><<<dim3(nseg, BATCH), 512, 0, stream>>>(
            hf[cur], hb[cur], hf[cur ^ 1], hb[cur ^ 1], wA, wR, Z,
            li0, pmin, 255, segbase);
        cur ^= 1; pmin = segbase;
        // group 2: d = 256, 512 (2 layers), halo sum 768, S=256
        segbase = pmin + 768;
        nseg = (SEQ - segbase + 255) / 256;
        k_fused8<2, 256, 512, 1><<<dim3(nseg, BATCH), 512, 0, stream>>>(
            hf[cur], hb[cur], hf[cur ^ 1], hb[cur ^ 1], wA, wR, Z,
            li0 + 8, pmin, 768, segbase);
        cur ^= 1; pmin = segbase;
    }

    k_skip_8ph<<<dim3(256), 512, 0, stream>>>(Z, wskB, skipb);
    k_end_m97<<<dim3(512), 256, 0, stream>>>(skipb, ewB, eb, out);
}